// Round 3
// baseline (6763.394 us; speedup 1.0000x reference)
//
#include <hip/hip_runtime.h>
#include <math.h>

// DCRNN encoder as ONE persistent kernel.
// 64 groups (one per batch b) x 4 blocks (52-node slice each), 256 thr/block.
// Layer pipeline: wave w runs L0 at t=w and L1 at t=w-1; 2 group barriers/wave.
// Per phase: diffusion (S-frags persistent in VGPRs, X staged transposed in LDS,
// XOR-swizzled) + dense MFMA (pre-blocked W frags from L2) + fused epilogue.
// S2=2*S@S precomputed; x2 = S2@x0 - x0 with -x0 folded into W (W0' = W0-W2).
// States: f32 master (h0f/h1f) + bf16 [m][h] (mx*) + bf16 transposed [h][m] (xt*).

typedef unsigned short u16;
typedef unsigned int u32;
typedef short bf8 __attribute__((ext_vector_type(8)));
typedef u16 u16x4 __attribute__((ext_vector_type(4)));
typedef u16 u16x8 __attribute__((ext_vector_type(8)));
typedef float f32x4 __attribute__((ext_vector_type(4)));

constexpr int T_ = 24, B_ = 64, N_ = 207, H_ = 64;
constexpr int NP = 224;                 // padded node dim
constexpr int SBH = NP * H_;            // 14336 state elems per b
constexpr int BNH = B_ * N_ * H_;       // 847872

#define MFMA(a, bb, c) __builtin_amdgcn_mfma_f32_16x16x32_bf16(a, bb, c, 0, 0, 0)

__device__ __forceinline__ float b2f(u16 b) {
    u32 u = ((u32)b) << 16; float f; __builtin_memcpy(&f, &u, 4); return f;
}
__device__ __forceinline__ u16 f2b(float f) {
    u32 u; __builtin_memcpy(&u, &f, 4);
    return (u16)((u + 0x7FFF + ((u >> 16) & 1)) >> 16);
}
__device__ __forceinline__ float sigm(float v) { return 1.f / (1.f + __expf(-v)); }

// ---------------------------------------------------------------- S2 = 2*S@S
__global__ void s2_kernel(const float* __restrict__ S, float* __restrict__ S2) {
    const int n = blockIdx.x, m = threadIdx.x;
    if (m >= N_) return;
    float acc = 0.f;
    for (int k = 0; k < N_; ++k) acc += S[n * N_ + k] * S[k * N_ + m];
    S2[n * N_ + m] = 2.f * acc;
}

// --------------------------------------- per-block S fragment buffer (bf16)
// sfr[jb 4][rtp 8][ks 7][lane 64][8]; rtp<4: S rows, rtp>=4: S2 rows.
__global__ void sfr_build(const float* __restrict__ S, const float* __restrict__ S2,
                          u16* __restrict__ sfr) {
    int idx = blockIdx.x * 256 + threadIdx.x;
    if (idx >= 114688) return;
    int jj = idx & 7;
    int tmp = idx >> 3;
    int lane = tmp & 63; tmp >>= 6;
    int ks = tmp % 7; tmp /= 7;
    int rtp = tmp & 7, jb = tmp >> 3;
    int half = rtp >> 2, rt = rtp & 3;
    int node = jb * 52 + rt * 16 + (lane & 15);
    int k = ks * 32 + (lane >> 4) * 8 + jj;
    float v = 0.f;
    if (node < N_ && k < N_) v = half ? S2[node * N_ + k] : S[node * N_ + k];
    sfr[idx] = f2b(v);
}

// ------------------------------------------------ W blocked to fragment order
__global__ void wblk_build(const float* __restrict__ W, u16* __restrict__ out,
                           int OF, int total, int layer) {
    int idx = blockIdx.x * 256 + threadIdx.x;
    if (idx >= total) return;
    int j = idx & 7;
    int rest = idx >> 3;
    int o = rest % OF; rest /= OF;
    int kb = rest & 3, ks = rest >> 2;
    int k = ks * 32 + kb * 8 + j;
    int blk = k >> 6, d = k & 63;
    int wrow, wsub = -1;
    if (layer == 0) {                       // [x0h, x1h, x2h], D=66
        wrow = blk * 66 + 2 + d;
        if (blk == 0) wsub = 2 * 66 + 2 + d;
    } else {                                // [x0x,x0h,x1x,x1h,x2x,x2h], D=128
        int sb = blk >> 1, part = blk & 1;
        wrow = sb * 128 + part * 64 + d;
        if (sb == 0) wsub = 256 + part * 64 + d;
    }
    float v = W[wrow * OF + o];
    if (wsub >= 0) v -= W[wsub * OF + o];
    out[idx] = f2b(v);
}

// ------------------------------------- layer-0 x-feature weight slice (f32)
__global__ void wx_build(const float* __restrict__ W, float* __restrict__ out, int OF) {
    int idx = blockIdx.x * 256 + threadIdx.x;
    if (idx >= 6 * OF) return;
    int o = idx % OF, p = idx / OF;
    int cheb = p >> 1, i = p & 1;
    float v = W[(cheb * 66 + i) * OF + o];
    if (cheb == 0) v -= W[(132 + i) * OF + o];
    out[idx] = v;
}

// ------------------------------------- x transpose: [T,B,N,2] -> [n][t][b][i]
__global__ void xt2_build(const float* __restrict__ x, u16* __restrict__ xt2) {
    int idx = blockIdx.x * 256 + threadIdx.x;
    if (idx >= N_ * T_ * B_ * 2) return;
    int i = idx & 1, b = (idx >> 1) & 63, rest = idx >> 7;
    int t = rest % T_, n = rest / T_;
    xt2[idx] = f2b(x[((t * B_ + b) * N_ + n) * 2 + i]);
}

// ----------------- layer-0 x part, all T: xpack[b][t][n][8] = [x0,x1,S@x,S2@x]
__global__ __launch_bounds__(256) void xpack_build(const float* __restrict__ S,
                                                   const float* __restrict__ S2,
                                                   const u16* __restrict__ xt2,
                                                   float* __restrict__ xpack) {
    __shared__ float sS[N_], sS2[N_];
    int n = blockIdx.x;
    for (int i = threadIdx.x; i < N_; i += 256) { sS[i] = S[n*N_+i]; sS2[i] = S2[n*N_+i]; }
    __syncthreads();
    int c = blockIdx.y * 256 + threadIdx.x;   // < 1536 = T*B
    float a10 = 0, a11 = 0, a20 = 0, a21 = 0;
    for (int m = 0; m < N_; ++m) {
        float x0 = b2f(xt2[m * 3072 + c * 2]);
        float x1 = b2f(xt2[m * 3072 + c * 2 + 1]);
        a10 += sS[m] * x0;  a11 += sS[m] * x1;
        a20 += sS2[m] * x0; a21 += sS2[m] * x1;
    }
    int t = c >> 6, bb = c & 63;
    float* p = xpack + (size_t)((bb * 24 + t) * N_ + n) * 8;
    p[0] = b2f(xt2[n * 3072 + c * 2]); p[1] = b2f(xt2[n * 3072 + c * 2 + 1]);
    p[2] = a10; p[3] = a11; p[4] = a20; p[5] = a21; p[6] = 0.f; p[7] = 0.f;
}

// ---------------------------------------------------------------- hidden init
__global__ void hinit_kernel(const float* __restrict__ ih,
                             float* __restrict__ h0f, float* __restrict__ h1f,
                             u16* __restrict__ mxH0, u16* __restrict__ mxH1,
                             u16* __restrict__ xtH0, u16* __restrict__ xtH1) {
    int idx = blockIdx.x * 256 + threadIdx.x;
    if (idx >= BNH) return;
    int h = idx & 63, n = (idx >> 6) % N_, b = (idx >> 6) / N_;
    float v0 = ih[(size_t)b * 13248 + n * 64 + h];
    float v1 = ih[(size_t)BNH + (size_t)b * 13248 + n * 64 + h];
    size_t si = (size_t)b * SBH + n * 64 + h;
    h0f[si] = v0; h1f[si] = v1;
    mxH0[si] = f2b(v0); mxH1[si] = f2b(v1);
    size_t ti = (size_t)b * SBH + h * NP + n;
    xtH0[ti] = f2b(v0); xtH1[ti] = f2b(v1);
}

// ------------------------------------------------------------- persistent scan
__global__ __launch_bounds__(256, 2) void dcrnn_persist(
    const u16* __restrict__ sfr,
    const u16* __restrict__ wg0b, const float* __restrict__ bg0, const float* __restrict__ wxg0,
    const u16* __restrict__ wc0b, const float* __restrict__ bc0, const float* __restrict__ wxc0,
    const u16* __restrict__ wg1b, const float* __restrict__ bg1,
    const u16* __restrict__ wc1b, const float* __restrict__ bc1,
    const float* __restrict__ xpack,
    u16* __restrict__ xtH0, u16* __restrict__ xtH1,
    u16* __restrict__ xtR0, u16* __restrict__ xtR1,
    u16* __restrict__ mxH0, u16* __restrict__ mxH1,
    u16* __restrict__ mxR0, u16* __restrict__ mxR1,
    float* __restrict__ h0f, float* __restrict__ h1f,
    u16* __restrict__ xh0d, u32* __restrict__ bar,
    float* __restrict__ out_hid, float* __restrict__ out_cur)
{
    __shared__ char lds[61440];
    char* ldsXT = lds;              // 28672: X transposed [h 64][m 224], XOR swz
    char* xcP   = lds + 28672;      // 16384: diff out [row 64][x1 64|x2 64]
    char* xcQ   = lds + 45056;      // 16384

    const int tid = threadIdx.x;
    const int lane = tid & 63, wid = tid >> 6;
    const int lq = lane >> 4, lr = lane & 15;
    const int bid = blockIdx.x;
    const int xcd = bid & 7, qq = bid >> 3;
    const int gin = qq >> 2, j = qq & 3;      // group-in-xcd, block-in-group
    const int b = xcd * 8 + gin;              // batch element = group id
    const int nj = j * 52;
    const int nReal = (j == 3) ? 51 : 52;
    const size_t sb = (size_t)b * SBH;

    // persistent S fragments: wave owns rows [wid*16,..) of both halves
    bf8 s0[7], s1[7];
#pragma unroll
    for (int ks = 0; ks < 7; ++ks) {
        s0[ks] = *(const bf8*)(sfr + (size_t)(((j * 8 + wid) * 7 + ks) * 64 + lane) * 8);
        s1[ks] = *(const bf8*)(sfr + (size_t)(((j * 8 + 4 + wid) * 7 + ks) * 64 + lane) * 8);
    }

    float u0[4][4], u1[4][4];
#pragma unroll
    for (int a = 0; a < 4; ++a)
#pragma unroll
        for (int c = 0; c < 4; ++c) { u0[a][c] = 0.f; u1[a][c] = 0.f; }

    u32 bar_target = 0;
    u32* mybar = bar + b * 16;   // 64B stride per group
    auto gbar = [&]() {
        __syncthreads();
        __threadfence();
        if (tid == 0)
            __hip_atomic_fetch_add(mybar, 1u, __ATOMIC_RELEASE, __HIP_MEMORY_SCOPE_AGENT);
        bar_target += 4;
        while (__hip_atomic_load(mybar, __ATOMIC_ACQUIRE, __HIP_MEMORY_SCOPE_AGENT) < bar_target)
            __builtin_amdgcn_s_sleep(2);
        __threadfence();
    };

    auto stageXT = [&](const u16* xtg) {
        const char* src = (const char*)(xtg + sb);
#pragma unroll
        for (int it = 0; it < 7; ++it) {
            int id = it * 256 + tid;
            int hrow = id / 28, mc = id - hrow * 28;
            int off = hrow * 448 + mc * 16;
            *(u16x8*)(ldsXT + (off ^ ((hrow & 7) << 4))) = *(const u16x8*)(src + off);
        }
    };

    auto diffuse = [&](char* xc) {
        f32x4 a0[4] = {{0,0,0,0},{0,0,0,0},{0,0,0,0},{0,0,0,0}};
        f32x4 a1[4] = {{0,0,0,0},{0,0,0,0},{0,0,0,0},{0,0,0,0}};
#pragma unroll
        for (int ks = 0; ks < 7; ++ks) {
#pragma unroll
            for (int ct = 0; ct < 4; ++ct) {
                int h = ct * 16 + lr;
                bf8 Bv = *(const bf8*)(ldsXT + ((h * 448 + ks * 64 + lq * 16) ^ ((h & 7) << 4)));
                a0[ct] = MFMA(s0[ks], Bv, a0[ct]);
                a1[ct] = MFMA(s1[ks], Bv, a1[ct]);
            }
        }
#pragma unroll
        for (int ct = 0; ct < 4; ++ct)
#pragma unroll
            for (int jj = 0; jj < 4; ++jj) {
                int row = wid * 16 + lq * 4 + jj;
                int sw = (row & 7) << 4;
                int k2 = (ct * 16 + lr) * 2;
                *(u16*)(xc + ((row * 256 + k2) ^ sw))       = f2b(a0[ct][jj]);
                *(u16*)(xc + ((row * 256 + 128 + k2) ^ sw)) = f2b(a1[ct][jj]);
            }
    };

    auto ldW = [&](const u16* w, int OF, int ks, int o) -> bf8 {
        return *(const bf8*)(w + (size_t)((ks * 4 + lq) * OF + o) * 8);
    };
    auto ldA_mx = [&](const u16* mx, int rt, int kel) -> bf8 {
        return *(const bf8*)(mx + sb + (size_t)(nj + rt * 16 + lr) * 64 + kel);
    };
    auto ldA_xc = [&](const char* xc, int rt, int kel) -> bf8 {
        int row = rt * 16 + lr;
        return *(const bf8*)(xc + ((row * 256 + kel * 2) ^ ((row & 7) << 4)));
    };
    auto ldA_xh = [&](int rt, int kel) -> bf8 {
        return *(const bf8*)(xh0d + (size_t)((b * 4 + j) * 64 + rt * 16 + lr) * 128 + kel);
    };

    char* ldsTr = ldsXT + wid * 2048;       // wave-private transpose staging
    auto trPut = [&](int row, float v) {
        *(u16*)(ldsTr + ((lr * 128 + row * 2) ^ ((lr & 7) << 4))) = f2b(v);
    };
    auto trFlush = [&](u16* xtg, int o0) {
        for (int it = lane; it < 208; it += 64) {     // 16 o-rows x 13 chunks of 4 m
            int ol = it / 13, r4 = it - ol * 13;
            u16x4 v = *(const u16x4*)(ldsTr + ((ol * 128 + r4 * 8) ^ ((ol & 7) << 4)));
            *(u16x4*)((char*)(xtg + sb) + (o0 + ol) * 448 + (nj + r4 * 4) * 2) = v;
        }
    };

    auto saveXh = [&]() {   // xcP (h0 diffusion) -> global, linear layout [64][128]
        for (int it = tid; it < 1024; it += 256) {
            int row = it >> 4, kc = it & 15;
            u16x8 v = *(const u16x8*)(xcP + ((row * 256 + kc * 16) ^ ((row & 7) << 4)));
            *(u16x8*)((char*)xh0d + (size_t)((b * 4 + j) * 64 + row) * 256 + kc * 16) = v;
        }
    };

    auto dense_g0 = [&](int t) {
        f32x4 acc[4][2] = {};
#pragma unroll
        for (int ks = 0; ks < 6; ++ks) {
            bf8 W0 = ldW(wg0b, 128, ks, wid * 16 + lr);
            bf8 W1 = ldW(wg0b, 128, ks, (wid + 4) * 16 + lr);
#pragma unroll
            for (int rt = 0; rt < 4; ++rt) {
                bf8 Av = (ks < 2) ? ldA_mx(mxH0, rt, ks * 32 + lq * 8)
                       : (ks < 4) ? ldA_xc(xcP, rt, (ks - 2) * 32 + lq * 8)
                                  : ldA_xc(xcP, rt, 64 + (ks - 4) * 32 + lq * 8);
                acc[rt][0] = MFMA(Av, W0, acc[rt][0]);
                acc[rt][1] = MFMA(Av, W1, acc[rt][1]);
            }
        }
        int oR = wid * 16 + lr, oU = oR + 64;
        float wxr[6], wxu[6];
#pragma unroll
        for (int p = 0; p < 6; ++p) { wxr[p] = wxg0[p * 128 + oR]; wxu[p] = wxg0[p * 128 + oU]; }
        float bR = bg0[oR], bU = bg0[oU];
#pragma unroll
        for (int rt = 0; rt < 4; ++rt)
#pragma unroll
            for (int jj = 0; jj < 4; ++jj) {
                int row = rt * 16 + lq * 4 + jj;
                float vR = acc[rt][0][jj] + bR, vU = acc[rt][1][jj] + bU;
                if (row < nReal) {
                    const float* xp = xpack + (size_t)((b * 24 + t) * N_ + nj + row) * 8;
#pragma unroll
                    for (int p = 0; p < 6; ++p) { vR += xp[p] * wxr[p]; vU += xp[p] * wxu[p]; }
                }
                float gR = sigm(vR);
                u0[rt][jj] = sigm(vU);
                float rh = gR * h0f[sb + (nj + row) * 64 + oR];
                if (row < nReal) mxR0[sb + (nj + row) * 64 + oR] = f2b(rh);
                trPut(row, rh);
            }
        trFlush(xtR0, wid * 16);
    };

    auto dense_g1 = [&]() {
        f32x4 acc[4][2] = {};
#pragma unroll
        for (int ks = 0; ks < 12; ++ks) {
            bf8 W0 = ldW(wg1b, 128, ks, wid * 16 + lr);
            bf8 W1 = ldW(wg1b, 128, ks, (wid + 4) * 16 + lr);
#pragma unroll
            for (int rt = 0; rt < 4; ++rt) {
                bf8 Av;
                if (ks < 2)       Av = ldA_mx(mxH0, rt, ks * 32 + lq * 8);
                else if (ks < 4)  Av = ldA_mx(mxH1, rt, (ks - 2) * 32 + lq * 8);
                else if (ks < 6)  Av = ldA_xc(xcP, rt, (ks - 4) * 32 + lq * 8);
                else if (ks < 8)  Av = ldA_xc(xcQ, rt, (ks - 6) * 32 + lq * 8);
                else if (ks < 10) Av = ldA_xc(xcP, rt, 64 + (ks - 8) * 32 + lq * 8);
                else              Av = ldA_xc(xcQ, rt, 64 + (ks - 10) * 32 + lq * 8);
                acc[rt][0] = MFMA(Av, W0, acc[rt][0]);
                acc[rt][1] = MFMA(Av, W1, acc[rt][1]);
            }
        }
        int oR = wid * 16 + lr, oU = oR + 64;
        float bR = bg1[oR], bU = bg1[oU];
#pragma unroll
        for (int rt = 0; rt < 4; ++rt)
#pragma unroll
            for (int jj = 0; jj < 4; ++jj) {
                int row = rt * 16 + lq * 4 + jj;
                float gR = sigm(acc[rt][0][jj] + bR);
                u1[rt][jj] = sigm(acc[rt][1][jj] + bU);
                float rh = gR * h1f[sb + (nj + row) * 64 + oR];
                if (row < nReal) mxR1[sb + (nj + row) * 64 + oR] = f2b(rh);
                trPut(row, rh);
            }
        trFlush(xtR1, wid * 16);
    };

    auto dense_c1 = [&](int w) {
        int t1 = w - 1;
        f32x4 acc[4] = {};
#pragma unroll
        for (int ks = 0; ks < 12; ++ks) {
            bf8 Wv = ldW(wc1b, 64, ks, wid * 16 + lr);
#pragma unroll
            for (int rt = 0; rt < 4; ++rt) {
                bf8 Av;
                if (ks < 2)       Av = ldA_mx(mxH0, rt, ks * 32 + lq * 8);
                else if (ks < 4)  Av = ldA_mx(mxR1, rt, (ks - 2) * 32 + lq * 8);
                else if (ks < 6)  Av = ldA_xh(rt, (ks - 4) * 32 + lq * 8);
                else if (ks < 8)  Av = ldA_xc(xcQ, rt, (ks - 6) * 32 + lq * 8);
                else if (ks < 10) Av = ldA_xh(rt, 64 + (ks - 8) * 32 + lq * 8);
                else              Av = ldA_xc(xcQ, rt, 64 + (ks - 10) * 32 + lq * 8);
                acc[rt] = MFMA(Av, Wv, acc[rt]);
            }
        }
        int o = wid * 16 + lr;
        float bv = bc1[o];
#pragma unroll
        for (int rt = 0; rt < 4; ++rt)
#pragma unroll
            for (int jj = 0; jj < 4; ++jj) {
                int row = rt * 16 + lq * 4 + jj;
                int n = nj + row;
                float cv = tanhf(acc[rt][jj] + bv);
                float hold = h1f[sb + n * 64 + o];
                float hn = u1[rt][jj] * hold + (1.f - u1[rt][jj]) * cv;
                if (row < nReal) {
                    h1f[sb + n * 64 + o] = hn;
                    mxH1[sb + n * 64 + o] = f2b(hn);
                    out_cur[(size_t)((t1 * 64 + b) * N_ + n) * 64 + o] = hn;
                }
                trPut(row, hn);
            }
        trFlush(xtH1, wid * 16);
    };

    auto dense_c0 = [&](int t) {
        f32x4 acc[4] = {};
#pragma unroll
        for (int ks = 0; ks < 6; ++ks) {
            bf8 Wv = ldW(wc0b, 64, ks, wid * 16 + lr);
#pragma unroll
            for (int rt = 0; rt < 4; ++rt) {
                bf8 Av = (ks < 2) ? ldA_mx(mxR0, rt, ks * 32 + lq * 8)
                       : (ks < 4) ? ldA_xc(xcP, rt, (ks - 2) * 32 + lq * 8)
                                  : ldA_xc(xcP, rt, 64 + (ks - 4) * 32 + lq * 8);
                acc[rt] = MFMA(Av, Wv, acc[rt]);
            }
        }
        int o = wid * 16 + lr;
        float bv = bc0[o];
        float wxc[6];
#pragma unroll
        for (int p = 0; p < 6; ++p) wxc[p] = wxc0[p * 64 + o];
#pragma unroll
        for (int rt = 0; rt < 4; ++rt)
#pragma unroll
            for (int jj = 0; jj < 4; ++jj) {
                int row = rt * 16 + lq * 4 + jj;
                int n = nj + row;
                float v = acc[rt][jj] + bv;
                if (row < nReal) {
                    const float* xp = xpack + (size_t)((b * 24 + t) * N_ + n) * 8;
#pragma unroll
                    for (int p = 0; p < 6; ++p) v += xp[p] * wxc[p];
                }
                float cv = tanhf(v);
                float hold = h0f[sb + n * 64 + o];
                float hn = u0[rt][jj] * hold + (1.f - u0[rt][jj]) * cv;
                if (row < nReal) {
                    h0f[sb + n * 64 + o] = hn;
                    mxH0[sb + n * 64 + o] = f2b(hn);
                }
                trPut(row, hn);
            }
        trFlush(xtH0, wid * 16);
    };

    // ------------------------------------------------ pipelined scan, 25 waves
    for (int w = 0; w <= 24; ++w) {
        const bool L0 = (w < 24), L1 = (w >= 1);
        // ---- PH1: gates (L0 at t=w, L1 at t=w-1)
        gbar();
        stageXT(xtH0); __syncthreads();
        diffuse(xcP);  __syncthreads();
        if (L1) { stageXT(xtH1); __syncthreads(); diffuse(xcQ); }
        __syncthreads();
        saveXh();
        if (L0) dense_g0(w);
        if (L1) dense_g1();
        // ---- PH2: candidates + state update (L1c first: reads OLD h0)
        gbar();
        if (L0) { stageXT(xtR0); __syncthreads(); diffuse(xcP); __syncthreads(); }
        if (L1) { stageXT(xtR1); __syncthreads(); diffuse(xcQ); }
        __syncthreads();
        if (L1) dense_c1(w);
        __syncthreads();
        if (L0) dense_c0(w);
    }

    // ---- final hidden state
    for (int it = tid; it < nReal * 64; it += 256) {
        int row = it >> 6, h = it & 63;
        int n = nj + row;
        out_hid[(size_t)b * 13248 + n * 64 + h] = h0f[sb + n * 64 + h];
        out_hid[(size_t)BNH + (size_t)b * 13248 + n * 64 + h] = h1f[sb + n * 64 + h];
    }
}

// ---------------------------------------------------------------------- launch
extern "C" void kernel_launch(void* const* d_in, const int* in_sizes, int n_in,
                              void* d_out, int out_size, void* d_ws, size_t ws_size,
                              hipStream_t stream) {
    const float* x   = (const float*)d_in[0];
    const float* ih  = (const float*)d_in[1];
    const float* S   = (const float*)d_in[2];
    const float* wg0 = (const float*)d_in[3];
    const float* bg0 = (const float*)d_in[4];
    const float* wc0 = (const float*)d_in[5];
    const float* bc0 = (const float*)d_in[6];
    const float* wg1 = (const float*)d_in[7];
    const float* bg1 = (const float*)d_in[8];
    const float* wc1 = (const float*)d_in[9];
    const float* bc1 = (const float*)d_in[10];

    char* p = (char*)d_ws;
    auto alloc = [&](size_t bytes) -> char* {
        char* r = p; p += (bytes + 255) & ~(size_t)255; return r;
    };
    float* S2    = (float*)alloc((size_t)N_ * N_ * 4);
    u16*   sfr   = (u16*)  alloc(114688 * 2);
    u16*   wg0b  = (u16*)  alloc(24576 * 2);
    u16*   wc0b  = (u16*)  alloc(12288 * 2);
    u16*   wg1b  = (u16*)  alloc(49152 * 2);
    u16*   wc1b  = (u16*)  alloc(24576 * 2);
    float* wxg0  = (float*)alloc(6 * 128 * 4);
    float* wxc0  = (float*)alloc(6 * 64 * 4);
    u16*   xt2   = (u16*)  alloc((size_t)N_ * 3072 * 2);
    float* xpack = (float*)alloc((size_t)64 * 24 * N_ * 8 * 4);
    u16*   xtH0  = (u16*)  alloc((size_t)B_ * SBH * 2);   // 8 contiguous bf16 state bufs
    u16*   xtH1  = (u16*)  alloc((size_t)B_ * SBH * 2);
    u16*   xtR0  = (u16*)  alloc((size_t)B_ * SBH * 2);
    u16*   xtR1  = (u16*)  alloc((size_t)B_ * SBH * 2);
    u16*   mxH0  = (u16*)  alloc((size_t)B_ * SBH * 2);
    u16*   mxH1  = (u16*)  alloc((size_t)B_ * SBH * 2);
    u16*   mxR0  = (u16*)  alloc((size_t)B_ * SBH * 2);
    u16*   mxR1  = (u16*)  alloc((size_t)B_ * SBH * 2);
    float* h0f   = (float*)alloc((size_t)B_ * SBH * 4);
    float* h1f   = (float*)alloc((size_t)B_ * SBH * 4);
    u16*   xh0d  = (u16*)  alloc((size_t)B_ * 4 * 64 * 128 * 2);
    u32*   bar   = (u32*)  alloc(64 * 64);

    float* out     = (float*)d_out;
    float* out_cur = out + 2 * (size_t)BNH;

    // zero bf16 state buffers (pads must be finite-zero) + barrier counters
    hipMemsetAsync(xtH0, 0, (size_t)8 * B_ * SBH * 2, stream);
    hipMemsetAsync(bar, 0, 64 * 64, stream);

    // ---- prep (parallel, before the persistent scan)
    s2_kernel  <<<N_, 256, 0, stream>>>(S, S2);
    sfr_build  <<<448, 256, 0, stream>>>(S, S2, sfr);
    wblk_build <<<96,  256, 0, stream>>>(wg0, wg0b, 128, 24576, 0);
    wblk_build <<<48,  256, 0, stream>>>(wc0, wc0b,  64, 12288, 0);
    wblk_build <<<192, 256, 0, stream>>>(wg1, wg1b, 128, 49152, 1);
    wblk_build <<<96,  256, 0, stream>>>(wc1, wc1b,  64, 24576, 1);
    wx_build   <<<3, 256, 0, stream>>>(wg0, wxg0, 128);
    wx_build   <<<2, 256, 0, stream>>>(wc0, wxc0, 64);
    xt2_build  <<<2484, 256, 0, stream>>>(x, xt2);
    xpack_build<<<dim3(N_, 6), 256, 0, stream>>>(S, S2, xt2, xpack);
    hinit_kernel<<<(BNH + 255) / 256, 256, 0, stream>>>(ih, h0f, h1f, mxH0, mxH1, xtH0, xtH1);

    // ---- persistent pipelined scan
    dcrnn_persist<<<256, 256, 0, stream>>>(
        sfr, wg0b, bg0, wxg0, wc0b, bc0, wxc0, wg1b, bg1, wc1b, bc1,
        xpack, xtH0, xtH1, xtR0, xtR1, mxH0, mxH1, mxR0, mxR1,
        h0f, h1f, xh0d, bar, out, out_cur);
}

// Round 4
// 5709.919 us; speedup vs baseline: 1.1845x; 1.1845x over previous
//
#include <hip/hip_runtime.h>
#include <math.h>

// DCRNN encoder: one block per batch element (64 blocks x 1024 thr), each block
// runs the full 24-step x 2-layer scan with NO inter-block sync.
// Per cell: Chebyshev diffusion via MFMA (S-frags cached in VGPRs per wave,
// X^T staged in LDS, XOR-swizzled) + dense MFMA (blocked W frags from L2) +
// fused sigmoid/tanh/GRU epilogue. S2=2*S@S precomputed; x2=S2@x0-x0 with -x0
// folded into W. Layer-0 x-part precomputed for all T (xpack).
// State: f32 master (global, L2-hot) + bf16 row-major mirrors (global) +
// bf16 transposed copies (LDS, persistent across the scan).

typedef unsigned short u16;
typedef unsigned int u32;
typedef short bf8 __attribute__((ext_vector_type(8)));
typedef u16 u16x4 __attribute__((ext_vector_type(4)));
typedef u16 u16x8 __attribute__((ext_vector_type(8)));
typedef float f32x4 __attribute__((ext_vector_type(4)));

constexpr int T_ = 24, B_ = 64, N_ = 207, H_ = 64;
constexpr int BNH = B_ * N_ * H_;      // 847872
constexpr int MXP  = 13312;            // 208*64 per-b pitch (elems)
constexpr int XCBP = 26624;            // 208*128 per-b pitch
constexpr int XTGP = 14336;            // 64*224 per-b pitch

// LDS offsets (total 139264 B)
constexpr int XT0 = 0;                 // [64 h][224 m] bf16, pitch 448B, XOR swz
constexpr int XT1 = 28672;
constexpr int XTR = 57344;
constexpr int XCA = 86016;             // [208 n][128 k] bf16, pitch 256B, XOR swz

#define MFMA(a, bb, c) __builtin_amdgcn_mfma_f32_16x16x32_bf16(a, bb, c, 0, 0, 0)

__device__ __forceinline__ float b2f(u16 b) {
    u32 u = ((u32)b) << 16; float f; __builtin_memcpy(&f, &u, 4); return f;
}
__device__ __forceinline__ u16 f2b(float f) {
    u32 u; __builtin_memcpy(&u, &f, 4);
    return (u16)((u + 0x7FFF + ((u >> 16) & 1)) >> 16);
}
__device__ __forceinline__ float sigm(float v) { return 1.f / (1.f + __expf(-v)); }
__device__ __forceinline__ float tanh_f(float v) {
    return 1.f - 2.f / (__expf(2.f * v) + 1.f);
}

// ---------------------------------------------------------------- S2 = 2*S@S
__global__ void s2_kernel(const float* __restrict__ S, float* __restrict__ S2) {
    const int n = blockIdx.x, m = threadIdx.x;
    if (m >= N_) return;
    float acc = 0.f;
    for (int k = 0; k < N_; ++k) acc += S[n * N_ + k] * S[k * N_ + m];
    S2[n * N_ + m] = 2.f * acc;
}

// ---------------------- S fragments: sfr[half 2][rt 13][ks 7][lane 64][j 8]
__global__ void sfr_build(const float* __restrict__ S, const float* __restrict__ S2,
                          u16* __restrict__ sfr) {
    int idx = blockIdx.x * 256 + threadIdx.x;
    if (idx >= 2 * 13 * 7 * 64 * 8) return;   // 93184
    int jj = idx & 7;
    int lane = (idx >> 3) & 63;
    int rest = idx >> 9;
    int ks = rest % 7; rest /= 7;
    int rt = rest % 13, half = rest / 13;
    int node = rt * 16 + (lane & 15);
    int k = ks * 32 + (lane >> 4) * 8 + jj;
    float v = 0.f;
    if (node < N_ && k < N_) v = half ? S2[node * N_ + k] : S[node * N_ + k];
    sfr[idx] = f2b(v);
}

// ------------------------------------------------ W blocked to fragment order
__global__ void wblk_build(const float* __restrict__ W, u16* __restrict__ out,
                           int OF, int total, int layer) {
    int idx = blockIdx.x * 256 + threadIdx.x;
    if (idx >= total) return;
    int j = idx & 7;
    int rest = idx >> 3;
    int o = rest % OF; rest /= OF;
    int kb = rest & 3, ks = rest >> 2;
    int k = ks * 32 + kb * 8 + j;
    int blk = k >> 6, d = k & 63;
    int wrow, wsub = -1;
    if (layer == 0) {                       // [x0h, x1h, x2h], D=66
        wrow = blk * 66 + 2 + d;
        if (blk == 0) wsub = 2 * 66 + 2 + d;
    } else {                                // [x0x,x0h,x1x,x1h,x2x,x2h], D=128
        int sb = blk >> 1, part = blk & 1;
        wrow = sb * 128 + part * 64 + d;
        if (sb == 0) wsub = 256 + part * 64 + d;
    }
    float v = W[wrow * OF + o];
    if (wsub >= 0) v -= W[wsub * OF + o];
    out[idx] = f2b(v);
}

// ------------------------------------- layer-0 x-feature weight slice (f32)
__global__ void wx_build(const float* __restrict__ W, float* __restrict__ out, int OF) {
    int idx = blockIdx.x * 256 + threadIdx.x;
    if (idx >= 6 * OF) return;
    int o = idx % OF, p = idx / OF;
    int cheb = p >> 1, i = p & 1;
    float v = W[(cheb * 66 + i) * OF + o];
    if (cheb == 0) v -= W[(132 + i) * OF + o];
    out[idx] = v;
}

// ------------------------------------- x transpose: [T,B,N,2] -> [n][t][b][i]
__global__ void xt2_build(const float* __restrict__ x, u16* __restrict__ xt2) {
    int idx = blockIdx.x * 256 + threadIdx.x;
    if (idx >= N_ * T_ * B_ * 2) return;
    int i = idx & 1, b = (idx >> 1) & 63, rest = idx >> 7;
    int t = rest % T_, n = rest / T_;
    xt2[idx] = f2b(x[((t * B_ + b) * N_ + n) * 2 + i]);
}

// ----------------- layer-0 x part, all T: xpack[b][t][n][8] = [x0,x1,S@x,S2@x]
__global__ __launch_bounds__(256) void xpack_build(const float* __restrict__ S,
                                                   const float* __restrict__ S2,
                                                   const u16* __restrict__ xt2,
                                                   float* __restrict__ xpack) {
    __shared__ float sS[N_], sS2[N_];
    int n = blockIdx.x;
    for (int i = threadIdx.x; i < N_; i += 256) { sS[i] = S[n*N_+i]; sS2[i] = S2[n*N_+i]; }
    __syncthreads();
    int c = blockIdx.y * 256 + threadIdx.x;   // < 1536 = T*B
    float a10 = 0, a11 = 0, a20 = 0, a21 = 0;
    for (int m = 0; m < N_; ++m) {
        float x0 = b2f(xt2[m * 3072 + c * 2]);
        float x1 = b2f(xt2[m * 3072 + c * 2 + 1]);
        a10 += sS[m] * x0;  a11 += sS[m] * x1;
        a20 += sS2[m] * x0; a21 += sS2[m] * x1;
    }
    int t = c >> 6, bb = c & 63;
    float* p = xpack + (size_t)((bb * 24 + t) * N_ + n) * 8;
    p[0] = b2f(xt2[n * 3072 + c * 2]); p[1] = b2f(xt2[n * 3072 + c * 2 + 1]);
    p[2] = a10; p[3] = a11; p[4] = a20; p[5] = a21; p[6] = 0.f; p[7] = 0.f;
}

// ---------------------------------------------------------------- hidden init
__global__ void hinit_kernel(const float* __restrict__ ih,
                             float* __restrict__ h0f, float* __restrict__ h1f,
                             u16* __restrict__ mxh0, u16* __restrict__ mxh1,
                             u16* __restrict__ xt0g, u16* __restrict__ xt1g) {
    int idx = blockIdx.x * 256 + threadIdx.x;
    if (idx >= BNH) return;
    int h = idx & 63, n = (idx >> 6) % N_, b = (idx >> 6) / N_;
    float v0 = ih[(size_t)b * 13248 + n * 64 + h];
    float v1 = ih[(size_t)BNH + (size_t)b * 13248 + n * 64 + h];
    h0f[(size_t)b * MXP + n * 64 + h] = v0;
    h1f[(size_t)b * MXP + n * 64 + h] = v1;
    mxh0[(size_t)b * MXP + n * 64 + h] = f2b(v0);
    mxh1[(size_t)b * MXP + n * 64 + h] = f2b(v1);
    xt0g[(size_t)b * XTGP + h * 224 + n] = f2b(v0);
    xt1g[(size_t)b * XTGP + h * 224 + n] = f2b(v1);
}

// --------------------------------------------------------------- scan kernel
__global__ __launch_bounds__(1024) void dcrnn_scan(
    const u16* __restrict__ sfr,
    const u16* __restrict__ wg0b, const float* __restrict__ bg0, const float* __restrict__ wxg0,
    const u16* __restrict__ wc0b, const float* __restrict__ bc0, const float* __restrict__ wxc0,
    const u16* __restrict__ wg1b, const float* __restrict__ bg1,
    const u16* __restrict__ wc1b, const float* __restrict__ bc1,
    const float* __restrict__ xpack,
    const u16* __restrict__ xt0g, const u16* __restrict__ xt1g,
    u16* __restrict__ mxh0, u16* __restrict__ mxh1, u16* __restrict__ mxr,
    u16* __restrict__ xcb,
    float* __restrict__ h0f, float* __restrict__ h1f,
    float* __restrict__ out_hid, float* __restrict__ out_cur)
{
    extern __shared__ char lds[];
    const int tid  = threadIdx.x;
    const int lane = tid & 63, wid = tid >> 6;
    const int lq = lane >> 4, lr = lane & 15;
    const int j = wid >> 2, rtg = wid & 3;
    const int j16 = j * 16;
    const int b = blockIdx.x;

    const u16*   mxh0b = mxh0 + (size_t)b * MXP;
    const u16*   mxh1b = mxh1 + (size_t)b * MXP;
    u16*   mxh0w = mxh0 + (size_t)b * MXP;
    u16*   mxh1w = mxh1 + (size_t)b * MXP;
    u16*   mxrb  = mxr  + (size_t)b * MXP;
    u16*   xcbB  = xcb  + (size_t)b * XCBP;
    float* h0fb  = h0f + (size_t)b * MXP;
    float* h1fb  = h1f + (size_t)b * MXP;

    // ---- startup: stage xt0/xt1 (swizzled), zero xtr
    {
        const char* g0 = (const char*)(xt0g + (size_t)b * XTGP);
        const char* g1 = (const char*)(xt1g + (size_t)b * XTGP);
        u16x8 z8 = {0,0,0,0,0,0,0,0};
        for (int i = tid; i < 1792; i += 1024) {
            int h = i / 28, c = i - h * 28;
            int off = h * 448 + c * 16;
            int swz = off ^ ((h & 7) << 4);
            *(u16x8*)(lds + XT0 + swz) = *(const u16x8*)(g0 + off);
            *(u16x8*)(lds + XT1 + swz) = *(const u16x8*)(g1 + off);
            *(u16x8*)(lds + XTR + off) = z8;
        }
    }
    __syncthreads();

    float uacc[4][4];
#pragma unroll
    for (int a = 0; a < 4; ++a)
#pragma unroll
        for (int c = 0; c < 4; ++c) uacc[a][c] = 0.f;

    // ---- diffusion: one row-tile rt, all 4 col-tiles; S/S2 frags cached
    auto diff_one = [&](int xt_off, int rt, bool toLds, u16* gdst) {
        bf8 A0[7], A1[7];
#pragma unroll
        for (int ks = 0; ks < 7; ++ks) {
            A0[ks] = *(const bf8*)(sfr + (size_t)(rt * 7 + ks) * 512 + lane * 8);
            A1[ks] = *(const bf8*)(sfr + (size_t)((13 + rt) * 7 + ks) * 512 + lane * 8);
        }
#pragma unroll
        for (int ct = 0; ct < 4; ++ct) {
            f32x4 a0 = {0,0,0,0}, a1 = {0,0,0,0};
            const int h = ct * 16 + lr;
            const int sw = (h & 7) << 4;
#pragma unroll
            for (int ks = 0; ks < 7; ++ks) {
                bf8 Bv = *(const bf8*)(lds + xt_off + ((h * 448 + ks * 64 + lq * 16) ^ sw));
                a0 = MFMA(A0[ks], Bv, a0);
                a1 = MFMA(A1[ks], Bv, a1);
            }
            if (toLds) {
#pragma unroll
                for (int jj = 0; jj < 4; ++jj) {
                    int row = rt * 16 + lq * 4 + jj;
                    int rs = (row & 7) << 4;
                    *(u16*)(lds + XCA + ((row * 256 + h * 2) ^ rs))       = f2b(a0[jj]);
                    *(u16*)(lds + XCA + ((row * 256 + 128 + h * 2) ^ rs)) = f2b(a1[jj]);
                }
            } else {
#pragma unroll
                for (int jj = 0; jj < 4; ++jj) {
                    int row = rt * 16 + lq * 4 + jj;
                    gdst[row * 128 + h]      = f2b(a0[jj]);
                    gdst[row * 128 + 64 + h] = f2b(a1[jj]);
                }
            }
        }
    };

    auto ldxcA = [&](int rt, int koff) -> bf8 {
        int row = rt * 16 + lr;
        return *(const bf8*)(lds + XCA + ((row * 256 + koff * 2) ^ ((row & 7) << 4)));
    };
    auto xtWrite = [&](int xt_off, int rt, u16x4 hv) {
        int o = j16 + lr;
        int nb = rt * 16 + lq * 4;
        *(u16x4*)(lds + xt_off + ((o * 448 + nb * 2) ^ ((o & 7) << 4))) = hv;
    };

    // ---------------------------------------------------------- dense phases
    auto dense_g0 = [&](const float* xpk) {
        f32x4 aR[4], aU[4];
#pragma unroll
        for (int i = 0; i < 4; ++i) { aR[i] = f32x4{0,0,0,0}; aU[i] = f32x4{0,0,0,0}; }
#pragma unroll
        for (int ks = 0; ks < 6; ++ks) {
            bf8 Wr = *(const bf8*)(wg0b + ((size_t)(ks * 4 + lq) * 128 + j16 + lr) * 8);
            bf8 Wu = *(const bf8*)(wg0b + ((size_t)(ks * 4 + lq) * 128 + 64 + j16 + lr) * 8);
#pragma unroll
            for (int i = 0; i < 4; ++i) {
                int rt = rtg + 4 * i; if (rt > 12) break;
                bf8 Av;
                if (ks < 2)      Av = *(const bf8*)(mxh0b + (rt * 16 + lr) * 64 + ks * 32 + lq * 8);
                else if (ks < 4) Av = ldxcA(rt, (ks - 2) * 32 + lq * 8);
                else             Av = ldxcA(rt, 64 + (ks - 4) * 32 + lq * 8);
                aR[i] = MFMA(Av, Wr, aR[i]);
                aU[i] = MFMA(Av, Wu, aU[i]);
            }
        }
        const int o = j16 + lr;
        const float bR = bg0[o], bU = bg0[64 + o];
#pragma unroll
        for (int i = 0; i < 4; ++i) {
            int rt = rtg + 4 * i; if (rt > 12) break;
            u16x4 hv;
#pragma unroll
            for (int jj = 0; jj < 4; ++jj) {
                int n = rt * 16 + lq * 4 + jj;
                float vR = aR[i][jj] + bR, vU = aU[i][jj] + bU;
                if (n < 207) {
                    const float* xp = xpk + n * 8;
#pragma unroll
                    for (int p = 0; p < 6; ++p) {
                        vR += xp[p] * wxg0[p * 128 + o];
                        vU += xp[p] * wxg0[p * 128 + 64 + o];
                    }
                }
                float r = sigm(vR);
                uacc[i][jj] = sigm(vU);
                float rh = r * h0fb[n * 64 + o];
                if (n < 207) mxrb[n * 64 + o] = f2b(rh);
                hv[jj] = f2b(rh);
            }
            xtWrite(XTR, rt, hv);
        }
    };

    auto dense_c0 = [&](const float* xpk) {
        f32x4 aC[4];
#pragma unroll
        for (int i = 0; i < 4; ++i) aC[i] = f32x4{0,0,0,0};
#pragma unroll
        for (int ks = 0; ks < 6; ++ks) {
            bf8 Wv = *(const bf8*)(wc0b + ((size_t)(ks * 4 + lq) * 64 + j16 + lr) * 8);
#pragma unroll
            for (int i = 0; i < 4; ++i) {
                int rt = rtg + 4 * i; if (rt > 12) break;
                bf8 Av;
                if (ks < 2)      Av = *(const bf8*)(mxrb + (rt * 16 + lr) * 64 + ks * 32 + lq * 8);
                else if (ks < 4) Av = ldxcA(rt, (ks - 2) * 32 + lq * 8);
                else             Av = ldxcA(rt, 64 + (ks - 4) * 32 + lq * 8);
                aC[i] = MFMA(Av, Wv, aC[i]);
            }
        }
        const int o = j16 + lr;
        const float bC = bc0[o];
#pragma unroll
        for (int i = 0; i < 4; ++i) {
            int rt = rtg + 4 * i; if (rt > 12) break;
            u16x4 hv;
#pragma unroll
            for (int jj = 0; jj < 4; ++jj) {
                int n = rt * 16 + lq * 4 + jj;
                float v = aC[i][jj] + bC;
                if (n < 207) {
                    const float* xp = xpk + n * 8;
#pragma unroll
                    for (int p = 0; p < 6; ++p) v += xp[p] * wxc0[p * 64 + o];
                }
                float cv = tanh_f(v);
                float hold = h0fb[n * 64 + o];
                float hn = uacc[i][jj] * hold + (1.f - uacc[i][jj]) * cv;
                if (n < 207) {
                    h0fb[n * 64 + o] = hn;
                    mxh0w[n * 64 + o] = f2b(hn);
                }
                hv[jj] = f2b(hn);
            }
            xtWrite(XT0, rt, hv);
        }
    };

    auto dense_g1 = [&]() {
        f32x4 aR[4], aU[4];
#pragma unroll
        for (int i = 0; i < 4; ++i) { aR[i] = f32x4{0,0,0,0}; aU[i] = f32x4{0,0,0,0}; }
#pragma unroll
        for (int ks = 0; ks < 12; ++ks) {
            bf8 Wr = *(const bf8*)(wg1b + ((size_t)(ks * 4 + lq) * 128 + j16 + lr) * 8);
            bf8 Wu = *(const bf8*)(wg1b + ((size_t)(ks * 4 + lq) * 128 + 64 + j16 + lr) * 8);
            const int fb = ks >> 1, koff = (ks & 1) * 32 + lq * 8;
#pragma unroll
            for (int i = 0; i < 4; ++i) {
                int rt = rtg + 4 * i; if (rt > 12) break;
                int row = rt * 16 + lr;
                bf8 Av;
                if (fb == 0)      Av = *(const bf8*)(mxh0b + row * 64 + koff);
                else if (fb == 1) Av = *(const bf8*)(mxh1b + row * 64 + koff);
                else if (fb == 2) Av = ldxcA(rt, koff);
                else if (fb == 3) Av = *(const bf8*)(xcbB + row * 128 + koff);
                else if (fb == 4) Av = ldxcA(rt, 64 + koff);
                else              Av = *(const bf8*)(xcbB + row * 128 + 64 + koff);
                aR[i] = MFMA(Av, Wr, aR[i]);
                aU[i] = MFMA(Av, Wu, aU[i]);
            }
        }
        const int o = j16 + lr;
        const float bR = bg1[o], bU = bg1[64 + o];
#pragma unroll
        for (int i = 0; i < 4; ++i) {
            int rt = rtg + 4 * i; if (rt > 12) break;
            u16x4 hv;
#pragma unroll
            for (int jj = 0; jj < 4; ++jj) {
                int n = rt * 16 + lq * 4 + jj;
                float r = sigm(aR[i][jj] + bR);
                uacc[i][jj] = sigm(aU[i][jj] + bU);
                float rh = r * h1fb[n * 64 + o];
                if (n < 207) mxrb[n * 64 + o] = f2b(rh);
                hv[jj] = f2b(rh);
            }
            xtWrite(XTR, rt, hv);
        }
    };

    auto dense_c1 = [&](int t) {
        f32x4 aC[4];
#pragma unroll
        for (int i = 0; i < 4; ++i) aC[i] = f32x4{0,0,0,0};
#pragma unroll
        for (int ks = 0; ks < 12; ++ks) {
            bf8 Wv = *(const bf8*)(wc1b + ((size_t)(ks * 4 + lq) * 64 + j16 + lr) * 8);
            const int fb = ks >> 1, koff = (ks & 1) * 32 + lq * 8;
#pragma unroll
            for (int i = 0; i < 4; ++i) {
                int rt = rtg + 4 * i; if (rt > 12) break;
                int row = rt * 16 + lr;
                bf8 Av;
                if (fb == 0)      Av = *(const bf8*)(mxh0b + row * 64 + koff);
                else if (fb == 1) Av = *(const bf8*)(mxrb + row * 64 + koff);
                else if (fb == 2) Av = ldxcA(rt, koff);
                else if (fb == 3) Av = *(const bf8*)(xcbB + row * 128 + koff);
                else if (fb == 4) Av = ldxcA(rt, 64 + koff);
                else              Av = *(const bf8*)(xcbB + row * 128 + 64 + koff);
                aC[i] = MFMA(Av, Wv, aC[i]);
            }
        }
        const int o = j16 + lr;
        const float bC = bc1[o];
        float* ocur = out_cur + (size_t)(t * B_ + b) * N_ * 64;
#pragma unroll
        for (int i = 0; i < 4; ++i) {
            int rt = rtg + 4 * i; if (rt > 12) break;
            u16x4 hv;
#pragma unroll
            for (int jj = 0; jj < 4; ++jj) {
                int n = rt * 16 + lq * 4 + jj;
                float cv = tanh_f(aC[i][jj] + bC);
                float hold = h1fb[n * 64 + o];
                float hn = uacc[i][jj] * hold + (1.f - uacc[i][jj]) * cv;
                if (n < 207) {
                    h1fb[n * 64 + o] = hn;
                    mxh1w[n * 64 + o] = f2b(hn);
                    ocur[(size_t)n * 64 + o] = hn;
                }
                hv[jj] = f2b(hn);
            }
            xtWrite(XT1, rt, hv);
        }
    };

    // --------------------------------------------------------------- the scan
    for (int t = 0; t < T_; ++t) {
        const float* xpk = xpack + (size_t)(b * 24 + t) * N_ * 8;
        // L0 gates
        if (wid < 13) diff_one(XT0, wid, true, nullptr);
        __syncthreads();
        dense_g0(xpk);
        __syncthreads();
        // L0 cand
        if (wid < 13) diff_one(XTR, wid, true, nullptr);
        __syncthreads();
        dense_c0(xpk);
        __syncthreads();
        // L1 gates: diffuse h0_new (-> xcA LDS) and h1 (-> xcB global)
        for (int itm = wid; itm < 26; itm += 16) {
            if (itm < 13) diff_one(XT0, itm, true, nullptr);
            else          diff_one(XT1, itm - 13, false, xcbB);
        }
        __syncthreads();
        dense_g1();
        __syncthreads();
        // L1 cand
        if (wid < 13) diff_one(XTR, wid, false, xcbB);
        __syncthreads();
        dense_c1(t);
        __syncthreads();
    }

    // ---- final hidden state
    for (int it = tid; it < 207 * 64; it += 1024) {
        out_hid[(size_t)b * 13248 + it] = h0fb[it];
        out_hid[(size_t)BNH + (size_t)b * 13248 + it] = h1fb[it];
    }
}

// ---------------------------------------------------------------------- launch
extern "C" void kernel_launch(void* const* d_in, const int* in_sizes, int n_in,
                              void* d_out, int out_size, void* d_ws, size_t ws_size,
                              hipStream_t stream) {
    const float* x   = (const float*)d_in[0];
    const float* ih  = (const float*)d_in[1];
    const float* S   = (const float*)d_in[2];
    const float* wg0 = (const float*)d_in[3];
    const float* bg0 = (const float*)d_in[4];
    const float* wc0 = (const float*)d_in[5];
    const float* bc0 = (const float*)d_in[6];
    const float* wg1 = (const float*)d_in[7];
    const float* bg1 = (const float*)d_in[8];
    const float* wc1 = (const float*)d_in[9];
    const float* bc1 = (const float*)d_in[10];

    char* p = (char*)d_ws;
    auto alloc = [&](size_t bytes) -> char* {
        char* r = p; p += (bytes + 255) & ~(size_t)255; return r;
    };
    float* S2    = (float*)alloc((size_t)N_ * N_ * 4);
    u16*   sfr   = (u16*)  alloc(93184 * 2);
    u16*   wg0b  = (u16*)  alloc(24576 * 2);
    u16*   wc0b  = (u16*)  alloc(12288 * 2);
    u16*   wg1b  = (u16*)  alloc(49152 * 2);
    u16*   wc1b  = (u16*)  alloc(24576 * 2);
    float* wxg0  = (float*)alloc(6 * 128 * 4);
    float* wxc0  = (float*)alloc(6 * 64 * 4);
    u16*   xt2   = (u16*)  alloc((size_t)N_ * 3072 * 2);
    float* xpack = (float*)alloc((size_t)B_ * 24 * N_ * 8 * 4);
    u16*   xt0g  = (u16*)  alloc((size_t)B_ * XTGP * 2);
    u16*   xt1g  = (u16*)  alloc((size_t)B_ * XTGP * 2);
    u16*   mxh0  = (u16*)  alloc((size_t)B_ * MXP * 2);
    u16*   mxh1  = (u16*)  alloc((size_t)B_ * MXP * 2);
    u16*   mxr   = (u16*)  alloc((size_t)B_ * MXP * 2);
    u16*   xcb   = (u16*)  alloc((size_t)B_ * XCBP * 2);
    float* h0f   = (float*)alloc((size_t)B_ * MXP * 4);
    float* h1f   = (float*)alloc((size_t)B_ * MXP * 4);

    float* out     = (float*)d_out;
    float* out_cur = out + 2 * (size_t)BNH;

    // ---- prep
    s2_kernel  <<<N_, 256, 0, stream>>>(S, S2);
    sfr_build  <<<364, 256, 0, stream>>>(S, S2, sfr);
    wblk_build <<<96,  256, 0, stream>>>(wg0, wg0b, 128, 24576, 0);
    wblk_build <<<48,  256, 0, stream>>>(wc0, wc0b,  64, 12288, 0);
    wblk_build <<<192, 256, 0, stream>>>(wg1, wg1b, 128, 49152, 1);
    wblk_build <<<96,  256, 0, stream>>>(wc1, wc1b,  64, 24576, 1);
    wx_build   <<<3, 256, 0, stream>>>(wg0, wxg0, 128);
    wx_build   <<<2, 256, 0, stream>>>(wc0, wxc0, 64);
    xt2_build  <<<2484, 256, 0, stream>>>(x, xt2);
    xpack_build<<<dim3(N_, 6), 256, 0, stream>>>(S, S2, xt2, xpack);
    hinit_kernel<<<(BNH + 255) / 256, 256, 0, stream>>>(ih, h0f, h1f, mxh0, mxh1, xt0g, xt1g);

    // ---- the whole scan: 64 independent blocks, no inter-block sync
    dcrnn_scan<<<64, 1024, 139264, stream>>>(
        sfr, wg0b, bg0, wxg0, wc0b, bc0, wxc0, wg1b, bg1, wc1b, bc1,
        xpack, xt0g, xt1g, mxh0, mxh1, mxr, xcb, h0f, h1f, out, out_cur);
}